// Round 1
// baseline (11827.867 us; speedup 1.0000x reference)
//
#include <hip/hip_runtime.h>
#include <stdint.h>
#include <math.h>

#define EPS 1e-5f

// ---------------------------------------------------------------------------
// helpers
// ---------------------------------------------------------------------------
__device__ __forceinline__ float bn_apply(const float* __restrict__ bnp, int C, int c, float x) {
    float g = bnp[c], b = bnp[C + c], m = bnp[2 * C + c], v = bnp[3 * C + c];
    float scale = g / sqrtf(v + EPS);
    return (x - m) * scale + b;
}

// ---------------------------------------------------------------------------
// conv1: fp32 direct conv, in [128,3,224,224], w [96,3,11,11], stride 4, pad 2
// out [128,96,55,55]
// ---------------------------------------------------------------------------
__global__ __launch_bounds__(256) void conv1_kernel(
    const float* __restrict__ x, const float* __restrict__ w, float* __restrict__ out)
{
    const int b = blockIdx.z, o = blockIdx.y;
    __shared__ float wl[363];
    for (int i = threadIdx.x; i < 363; i += 256) wl[i] = w[o * 363 + i];
    __syncthreads();
    int pos = blockIdx.x * 256 + threadIdx.x;
    if (pos >= 55 * 55) return;
    int oy = pos / 55, ox = pos % 55;
    const float* xb = x + (size_t)b * 3 * 224 * 224;
    float acc = 0.f;
    #pragma unroll
    for (int c = 0; c < 3; ++c) {
        #pragma unroll
        for (int kh = 0; kh < 11; ++kh) {
            int iy = 4 * oy + kh - 2;
            if ((unsigned)iy >= 224u) continue;
            const float* row = xb + ((size_t)c * 224 + iy) * 224;
            const float* wr = wl + (c * 11 + kh) * 11;
            #pragma unroll
            for (int kw = 0; kw < 11; ++kw) {
                int ix = 4 * ox + kw - 2;
                if ((unsigned)ix < 224u) acc = fmaf(row[ix], wr[kw], acc);
            }
        }
    }
    out[((size_t)(b * 96 + o) * 55 + oy) * 55 + ox] = acc;
}

// ---------------------------------------------------------------------------
// fused maxpool(3x3, stride2, VALID) + BN (pool BEFORE bn, per reference)
// ---------------------------------------------------------------------------
__global__ __launch_bounds__(256) void pool_bn_kernel(
    const float* __restrict__ in, float* __restrict__ out,
    const float* __restrict__ bnp,
    int C, int Hi, int Wi, int Ho, int Wo, int total)
{
    int idx = blockIdx.x * 256 + threadIdx.x;
    if (idx >= total) return;
    int x = idx % Wo, t = idx / Wo;
    int y = t % Ho; t /= Ho;
    int c = t % C;  int b = t / C;
    const float* base = in + ((size_t)(b * C + c) * Hi + 2 * y) * Wi + 2 * x;
    float m = -INFINITY;
    #pragma unroll
    for (int j = 0; j < 3; ++j)
        #pragma unroll
        for (int i = 0; i < 3; ++i)
            m = fmaxf(m, base[(size_t)j * Wi + i]);
    out[idx] = bn_apply(bnp, C, c, m);
}

// ---------------------------------------------------------------------------
// binarize + pad(-1) + bitpack along C: in [B,C,H,W] fp32 ->
// out [B, C/32, H+2p, W+2p] u32, bit j = (value < 0), pad word = all ones
// ---------------------------------------------------------------------------
__global__ __launch_bounds__(256) void binpack_pad_kernel(
    const float* __restrict__ in, uint32_t* __restrict__ out,
    int C, int H, int W, int pad, int Hp, int Wp, int total)
{
    int idx = blockIdx.x * 256 + threadIdx.x;
    if (idx >= total) return;
    int xp = idx % Wp, t = idx / Wp;
    int yp = t % Hp; t /= Hp;
    int cw = t % (C / 32); int b = t / (C / 32);
    int x = xp - pad, y = yp - pad;
    uint32_t word;
    if ((unsigned)x >= (unsigned)W || (unsigned)y >= (unsigned)H) {
        word = 0xFFFFFFFFu;  // pad value -1 -> negative -> bit 1
    } else {
        word = 0u;
        const float* base = in + ((size_t)(b * C + cw * 32) * H + y) * W + x;
        const size_t hw = (size_t)H * W;
        #pragma unroll
        for (int j = 0; j < 32; ++j)
            word |= (base[hw * j] < 0.f) ? (1u << j) : 0u;
    }
    out[idx] = word;
}

// pack conv weights [O,C,KH,KW] -> [O, C/32, KH*KW] u32 (bit j = channel cw*32+j)
__global__ __launch_bounds__(256) void packw_kernel(
    const float* __restrict__ w, uint32_t* __restrict__ out,
    int C, int KK, int total)
{
    int idx = blockIdx.x * 256 + threadIdx.x;
    if (idx >= total) return;
    int kk = idx % KK, t = idx / KK;
    int cw = t % (C / 32); int o = t / (C / 32);
    const float* base = w + ((size_t)o * C + cw * 32) * KK + kk;
    uint32_t word = 0;
    #pragma unroll
    for (int j = 0; j < 32; ++j)
        word |= (base[(size_t)j * KK] < 0.f) ? (1u << j) : 0u;
    out[idx] = word;
}

// pack a row-major [rows, N] fp32 tensor along N into [rows, N/32] u32
__global__ __launch_bounds__(256) void packflat_kernel(
    const float* __restrict__ in, uint32_t* __restrict__ out, int total)
{
    int idx = blockIdx.x * 256 + threadIdx.x;
    if (idx >= total) return;
    const float* base = in + (size_t)idx * 32;
    uint32_t word = 0;
    #pragma unroll
    for (int j = 0; j < 32; ++j)
        word |= (base[j] < 0.f) ? (1u << j) : 0u;
    out[idx] = word;
}

// ---------------------------------------------------------------------------
// binary conv via XOR+popcount. act [B,CW,Hp,Wp] u32, wt [O,CW,KH*KW] u32.
// dot = Kbits - 2*popsum. Optional fused bn (bnp != nullptr).
// ---------------------------------------------------------------------------
template <int CW, int KH, int KW>
__global__ __launch_bounds__(256) void binconv_kernel(
    const uint32_t* __restrict__ pa, const uint32_t* __restrict__ pw,
    float* __restrict__ out, const float* __restrict__ bnp,
    int Hp, int Wp, int Ho, int Wo, int O, int Kbits)
{
    const int b = blockIdx.z, o = blockIdx.y;
    constexpr int NW = CW * KH * KW;
    __shared__ uint32_t wl[NW];
    for (int i = threadIdx.x; i < NW; i += 256) wl[i] = pw[(size_t)o * NW + i];
    __syncthreads();
    int pos = blockIdx.x * 256 + threadIdx.x;
    if (pos >= Ho * Wo) return;
    int y = pos / Wo, x = pos % Wo;
    const uint32_t* pab = pa + (size_t)b * CW * Hp * Wp;
    int sum = 0;
    #pragma unroll
    for (int cw = 0; cw < CW; ++cw) {
        #pragma unroll
        for (int kh = 0; kh < KH; ++kh) {
            const uint32_t* row = pab + ((size_t)(cw * Hp) + y + kh) * Wp + x;
            const uint32_t* wr = wl + (cw * KH + kh) * KW;
            #pragma unroll
            for (int kw = 0; kw < KW; ++kw)
                sum += __popc(row[kw] ^ wr[kw]);
        }
    }
    float dot = (float)(Kbits - 2 * sum);
    if (bnp) dot = bn_apply(bnp, O, o, dot);
    out[((size_t)(b * O + o) * Ho + y) * Wo + x] = dot;
}

// ---------------------------------------------------------------------------
// binary FC: out[b,o] = Kbits - 2*popcount(x[b,:] ^ w[o,:]), + bn (+relu)
// ---------------------------------------------------------------------------
template <int KWRD>
__global__ __launch_bounds__(256) void bingemm_kernel(
    const uint32_t* __restrict__ xp, const uint32_t* __restrict__ wp,
    float* __restrict__ out, const float* __restrict__ bnp,
    int Kbits, int O, int relu)
{
    const int b = blockIdx.y;
    __shared__ uint32_t xl[KWRD];
    for (int i = threadIdx.x; i < KWRD; i += 256) xl[i] = xp[(size_t)b * KWRD + i];
    __syncthreads();
    int o = blockIdx.x * 256 + threadIdx.x;
    if (o >= O) return;
    const uint32_t* wr = wp + (size_t)o * KWRD;
    int sum = 0;
    #pragma unroll 4
    for (int k = 0; k < KWRD; ++k) sum += __popc(xl[k] ^ wr[k]);
    float dot = (float)(Kbits - 2 * sum);
    if (bnp) dot = bn_apply(bnp, O, o, dot);
    if (relu) dot = fmaxf(dot, 0.f);
    out[(size_t)b * O + o] = dot;
}

// ---------------------------------------------------------------------------
// fc3: [128,4096] x [1000,4096]^T + bias. Register-tiled fp32 with K-split
// for parallelism. part layout: [ksplit=8][128][1024]
// ---------------------------------------------------------------------------
__global__ __launch_bounds__(256) void fc3_partial_kernel(
    const float* __restrict__ in, const float* __restrict__ w, float* __restrict__ part)
{
    const int otile = blockIdx.x * 64;
    const int kbase = blockIdx.y * 512;
    __shared__ float xs[32][132];
    __shared__ float wt[32][68];
    const int tid = threadIdx.x;
    const int ox = (tid & 15) * 4;   // 4 consecutive o per thread
    const int bx = (tid >> 4) * 8;   // 8 consecutive b per thread
    float acc[4][8];
    #pragma unroll
    for (int i = 0; i < 4; ++i)
        #pragma unroll
        for (int j = 0; j < 8; ++j) acc[i][j] = 0.f;

    for (int kc = 0; kc < 512; kc += 32) {
        __syncthreads();
        #pragma unroll
        for (int j = 0; j < 16; ++j) {          // 4096 x-tile elems
            int idx = tid + j * 256;
            int bb = idx >> 5, kk = idx & 31;
            xs[kk][bb] = in[(size_t)bb * 4096 + kbase + kc + kk];
        }
        #pragma unroll
        for (int j = 0; j < 8; ++j) {           // 2048 w-tile elems
            int idx = tid + j * 256;
            int oo = idx >> 5, kk = idx & 31;
            int og = otile + oo;
            wt[kk][oo] = (og < 1000) ? w[(size_t)og * 4096 + kbase + kc + kk] : 0.f;
        }
        __syncthreads();
        #pragma unroll
        for (int kk = 0; kk < 32; ++kk) {
            float4 wv = *(const float4*)&wt[kk][ox];
            float4 x0 = *(const float4*)&xs[kk][bx];
            float4 x1 = *(const float4*)&xs[kk][bx + 4];
            float wvv[4] = {wv.x, wv.y, wv.z, wv.w};
            float xv[8]  = {x0.x, x0.y, x0.z, x0.w, x1.x, x1.y, x1.z, x1.w};
            #pragma unroll
            for (int i = 0; i < 4; ++i)
                #pragma unroll
                for (int j = 0; j < 8; ++j)
                    acc[i][j] = fmaf(wvv[i], xv[j], acc[i][j]);
        }
    }
    float* pb = part + (size_t)blockIdx.y * 128 * 1024;
    #pragma unroll
    for (int i = 0; i < 4; ++i)
        #pragma unroll
        for (int j = 0; j < 8; ++j)
            pb[(size_t)(bx + j) * 1024 + otile + ox + i] = acc[i][j];
}

__global__ __launch_bounds__(256) void fc3_reduce_kernel(
    const float* __restrict__ part, const float* __restrict__ bias,
    float* __restrict__ out)
{
    int idx = blockIdx.x * 256 + threadIdx.x;  // b*1000 + o
    if (idx >= 128 * 1000) return;
    int o = idx % 1000, b = idx / 1000;
    float s = bias[o];
    #pragma unroll
    for (int k = 0; k < 8; ++k)
        s += part[((size_t)k * 128 + b) * 1024 + o];
    out[idx] = s;
}

// ---------------------------------------------------------------------------
// launch
// ---------------------------------------------------------------------------
extern "C" void kernel_launch(void* const* d_in, const int* in_sizes, int n_in,
                              void* d_out, int out_size, void* d_ws, size_t ws_size,
                              hipStream_t stream)
{
    const float* x        = (const float*)d_in[0];
    const float* conv1_w  = (const float*)d_in[1];
    const float* bconv2_w = (const float*)d_in[2];
    const float* bconv3_w = (const float*)d_in[3];
    const float* bconv4_w = (const float*)d_in[4];
    const float* bconv5_w = (const float*)d_in[5];
    const float* blin1_w  = (const float*)d_in[6];
    const float* blin2_w  = (const float*)d_in[7];
    const float* lin3_w   = (const float*)d_in[8];
    const float* lin3_b   = (const float*)d_in[9];
    const float* bn1 = (const float*)d_in[10];
    const float* bn2 = (const float*)d_in[11];
    const float* bn3 = (const float*)d_in[12];
    const float* bn4 = (const float*)d_in[13];
    const float* bn5 = (const float*)d_in[14];
    const float* bn6 = (const float*)d_in[15];
    const float* bn7 = (const float*)d_in[16];
    float* out = (float*)d_out;

    // workspace layout (bytes, all 256-aligned)
    char* ws = (char*)d_ws;
    float*    A    = (float*)(ws + 0);               // 148,684,800 B (conv1 out max)
    float*    Bb   = (float*)(ws + 148684800);       //  35,831,808 B
    uint32_t* PA   = (uint32_t*)(ws + 184516608);    //   1,476,096 B (packed acts)
    uint32_t* PW   = (uint32_t*)(ws + 185992704);    //     165,888 B (packed conv w)
    uint32_t* PWF1 = (uint32_t*)(ws + 186158592);    //   4,718,592 B
    uint32_t* PWF2 = (uint32_t*)(ws + 190877184);    //   2,097,152 B
    float*    PART = (float*)(ws + 192974336);       //   4,194,304 B
    // total: 197,168,640 B

    // 1) conv1 -> A [128,96,55,55]
    conv1_kernel<<<dim3(12, 96, 128), 256, 0, stream>>>(x, conv1_w, A);

    // 2) maxpool + bn1 -> Bb [128,96,27,27]
    {
        int total = 128 * 96 * 27 * 27;
        pool_bn_kernel<<<(total + 255) / 256, 256, 0, stream>>>(A, Bb, bn1, 96, 55, 55, 27, 27, total);
    }
    // 3) binarize+pad2+pack -> PA [128,3,31,31]
    {
        int total = 128 * 3 * 31 * 31;
        binpack_pad_kernel<<<(total + 255) / 256, 256, 0, stream>>>(Bb, PA, 96, 27, 27, 2, 31, 31, total);
    }
    // 4) pack bconv2_w -> PW [256,3,25]
    {
        int total = 256 * 3 * 25;
        packw_kernel<<<(total + 255) / 256, 256, 0, stream>>>(bconv2_w, PW, 96, 25, total);
    }
    // 5) binconv2 -> A [128,256,27,27]
    binconv_kernel<3, 5, 5><<<dim3(3, 256, 128), 256, 0, stream>>>(
        PA, PW, A, nullptr, 31, 31, 27, 27, 256, 2400);

    // 6) maxpool + bn2 -> Bb [128,256,13,13]
    {
        int total = 128 * 256 * 13 * 13;
        pool_bn_kernel<<<(total + 255) / 256, 256, 0, stream>>>(A, Bb, bn2, 256, 27, 27, 13, 13, total);
    }
    // 7) binarize+pad1+pack -> PA [128,8,15,15]
    {
        int total = 128 * 8 * 15 * 15;
        binpack_pad_kernel<<<(total + 255) / 256, 256, 0, stream>>>(Bb, PA, 256, 13, 13, 1, 15, 15, total);
    }
    // 8) pack bconv3_w
    {
        int total = 384 * 8 * 9;
        packw_kernel<<<(total + 255) / 256, 256, 0, stream>>>(bconv3_w, PW, 256, 9, total);
    }
    // 9) binconv3 + bn3 -> A [128,384,13,13]
    binconv_kernel<8, 3, 3><<<dim3(1, 384, 128), 256, 0, stream>>>(
        PA, PW, A, bn3, 15, 15, 13, 13, 384, 2304);

    // 10) binarize+pad1+pack -> PA [128,12,15,15]
    {
        int total = 128 * 12 * 15 * 15;
        binpack_pad_kernel<<<(total + 255) / 256, 256, 0, stream>>>(A, PA, 384, 13, 13, 1, 15, 15, total);
    }
    // 11) pack bconv4_w
    {
        int total = 384 * 12 * 9;
        packw_kernel<<<(total + 255) / 256, 256, 0, stream>>>(bconv4_w, PW, 384, 9, total);
    }
    // 12) binconv4 + bn4 -> Bb [128,384,13,13]
    binconv_kernel<12, 3, 3><<<dim3(1, 384, 128), 256, 0, stream>>>(
        PA, PW, Bb, bn4, 15, 15, 13, 13, 384, 3456);

    // 13) binarize+pad1+pack -> PA [128,12,15,15]
    {
        int total = 128 * 12 * 15 * 15;
        binpack_pad_kernel<<<(total + 255) / 256, 256, 0, stream>>>(Bb, PA, 384, 13, 13, 1, 15, 15, total);
    }
    // 14) pack bconv5_w
    {
        int total = 256 * 12 * 9;
        packw_kernel<<<(total + 255) / 256, 256, 0, stream>>>(bconv5_w, PW, 384, 9, total);
    }
    // 15) binconv5 (no bn) -> A [128,256,13,13]
    binconv_kernel<12, 3, 3><<<dim3(1, 256, 128), 256, 0, stream>>>(
        PA, PW, A, nullptr, 15, 15, 13, 13, 256, 3456);

    // 16) maxpool + bn5 -> Bb [128,256,6,6]  (flatten = [128,9216])
    {
        int total = 128 * 256 * 6 * 6;
        pool_bn_kernel<<<(total + 255) / 256, 256, 0, stream>>>(A, Bb, bn5, 256, 13, 13, 6, 6, total);
    }
    // 17) pack activations -> PA [128,288]
    {
        int total = 128 * 288;
        packflat_kernel<<<(total + 255) / 256, 256, 0, stream>>>(Bb, PA, total);
    }
    // 18) pack blin1_w -> PWF1 [4096,288]
    {
        int total = 4096 * 288;
        packflat_kernel<<<(total + 255) / 256, 256, 0, stream>>>(blin1_w, PWF1, total);
    }
    // 19) bingemm1 + bn6 -> A [128,4096]
    bingemm_kernel<288><<<dim3(16, 128), 256, 0, stream>>>(PA, PWF1, A, bn6, 9216, 4096, 0);

    // 20) pack activations -> PA [128,128]
    {
        int total = 128 * 128;
        packflat_kernel<<<(total + 255) / 256, 256, 0, stream>>>(A, PA, total);
    }
    // 21) pack blin2_w -> PWF2 [4096,128]
    {
        int total = 4096 * 128;
        packflat_kernel<<<(total + 255) / 256, 256, 0, stream>>>(blin2_w, PWF2, total);
    }
    // 22) bingemm2 + bn7 + relu -> Bb [128,4096]
    bingemm_kernel<128><<<dim3(16, 128), 256, 0, stream>>>(PA, PWF2, Bb, bn7, 4096, 4096, 1);

    // 23) fc3 partial (K-split 8) -> PART [8][128][1024]
    fc3_partial_kernel<<<dim3(16, 8), 256, 0, stream>>>(Bb, lin3_w, PART);

    // 24) reduce + bias -> d_out [128,1000]
    fc3_reduce_kernel<<<(128 * 1000 + 255) / 256, 256, 0, stream>>>(PART, lin3_b, out);
}

// Round 2
// 1930.311 us; speedup vs baseline: 6.1274x; 6.1274x over previous
//
#include <hip/hip_runtime.h>
#include <stdint.h>
#include <math.h>

#define EPS 1e-5f

typedef float f4a4 __attribute__((ext_vector_type(4), aligned(4)));

// ---------------------------------------------------------------------------
// helpers
// ---------------------------------------------------------------------------
__device__ __forceinline__ float bn_apply(const float* __restrict__ bnp, int C, int c, float x) {
    float g = bnp[c], b = bnp[C + c], m = bnp[2 * C + c], v = bnp[3 * C + c];
    float scale = g / sqrtf(v + EPS);
    return (x - m) * scale + b;
}

// ---------------------------------------------------------------------------
// conv1 weight transpose: w [96,3,11,11] -> wt2 [3][11][96][11]
// ---------------------------------------------------------------------------
__global__ __launch_bounds__(256) void conv1_transpose_w(
    const float* __restrict__ w, float* __restrict__ wt2)
{
    int idx = blockIdx.x * 256 + threadIdx.x;
    if (idx >= 96 * 363) return;
    int o = idx / 363, k = idx % 363;
    int c = k / 121, kh = (k / 11) % 11, kw = k % 11;
    wt2[((size_t)(c * 11 + kh) * 96 + o) * 11 + kw] = w[idx];
}

// ---------------------------------------------------------------------------
// conv1: fp32 direct conv, register-tiled.
// in [128,3,224,224], wt2 [3][11][96][11], stride 4, pad 2 -> out [128,96,55,55]
// grid (55, 3, 128), block 256.
// lane -> o = og*32 + (l&31); ox-octant g = (l>>5) + 2*wave; 7 ox per thread.
// ---------------------------------------------------------------------------
#define ROWW 236
__global__ __launch_bounds__(256) void conv1_kernel(
    const float* __restrict__ x, const float* __restrict__ wt2, float* __restrict__ out)
{
    const int oy = blockIdx.x;      // 0..54
    const int og = blockIdx.y;      // 0..2
    const int b  = blockIdx.z;      // 0..127
    __shared__ float lds[33 * ROWW];   // 31,152 B

    // stage 33 padded input rows (zero pad: left 2, right to ROWW, OOB rows)
    const float* xb = x + (size_t)b * 3 * 224 * 224;
    for (int idx = threadIdx.x; idx < 33 * ROWW; idx += 256) {
        int rall = idx / ROWW, pos = idx % ROWW;
        int c = rall / 11, kh = rall % 11;
        int iy = 4 * oy + kh - 2;
        int ix = pos - 2;
        float v = 0.f;
        if ((unsigned)iy < 224u && (unsigned)ix < 224u)
            v = xb[((size_t)c * 224 + iy) * 224 + ix];
        lds[idx] = v;
    }
    __syncthreads();

    const int l = threadIdx.x & 63;
    const int wv_ = threadIdx.x >> 6;
    const int o = og * 32 + (l & 31);
    const int g = (l >> 5) + 2 * wv_;   // 0..7
    float acc[7] = {0.f, 0.f, 0.f, 0.f, 0.f, 0.f, 0.f};

    for (int c = 0; c < 3; ++c) {
        #pragma unroll
        for (int kh = 0; kh < 11; ++kh) {
            // 11 weights for this (c,kh,o) — coalesced across lanes (stride 11)
            const float* wp = wt2 + ((size_t)(c * 11 + kh) * 96 + o) * 11;
            float wreg[11];
            f4a4 w0 = *(const f4a4*)&wp[0];
            f4a4 w1 = *(const f4a4*)&wp[4];
            f4a4 w2 = *(const f4a4*)&wp[7];
            wreg[0] = w0.x; wreg[1] = w0.y; wreg[2] = w0.z; wreg[3] = w0.w;
            wreg[4] = w1.x; wreg[5] = w1.y; wreg[6] = w1.z; wreg[7] = w1.w;
            wreg[8] = w2.y; wreg[9] = w2.z; wreg[10] = w2.w;
            // 36 input pixels for this (c,kh,g) from LDS (16B-aligned)
            const float* ip = lds + (c * 11 + kh) * ROWW + g * 28;
            float vin[36];
            #pragma unroll
            for (int q = 0; q < 9; ++q)
                *(float4*)&vin[4 * q] = *(const float4*)&ip[4 * q];
            #pragma unroll
            for (int kw = 0; kw < 11; ++kw)
                #pragma unroll
                for (int j = 0; j < 7; ++j)
                    acc[j] = fmaf(wreg[kw], vin[4 * j + kw], acc[j]);
        }
    }
    float* ob = out + ((size_t)(b * 96 + o) * 55 + oy) * 55;
    #pragma unroll
    for (int j = 0; j < 7; ++j) {
        int ox = g * 7 + j;
        if (ox < 55) ob[ox] = acc[j];
    }
}

// ---------------------------------------------------------------------------
// fused maxpool(3x3, stride2, VALID) + BN (pool BEFORE bn, per reference)
// ---------------------------------------------------------------------------
__global__ __launch_bounds__(256) void pool_bn_kernel(
    const float* __restrict__ in, float* __restrict__ out,
    const float* __restrict__ bnp,
    int C, int Hi, int Wi, int Ho, int Wo, int total)
{
    int idx = blockIdx.x * 256 + threadIdx.x;
    if (idx >= total) return;
    int x = idx % Wo, t = idx / Wo;
    int y = t % Ho; t /= Ho;
    int c = t % C;  int b = t / C;
    const float* base = in + ((size_t)(b * C + c) * Hi + 2 * y) * Wi + 2 * x;
    float m = -INFINITY;
    #pragma unroll
    for (int j = 0; j < 3; ++j)
        #pragma unroll
        for (int i = 0; i < 3; ++i)
            m = fmaxf(m, base[(size_t)j * Wi + i]);
    out[idx] = bn_apply(bnp, C, c, m);
}

// ---------------------------------------------------------------------------
// binarize + pad(-1) + bitpack along C: in [B,C,H,W] fp32 ->
// out [B, C/32, H+2p, W+2p] u32, bit j = (value < 0), pad word = all ones
// ---------------------------------------------------------------------------
__global__ __launch_bounds__(256) void binpack_pad_kernel(
    const float* __restrict__ in, uint32_t* __restrict__ out,
    int C, int H, int W, int pad, int Hp, int Wp, int total)
{
    int idx = blockIdx.x * 256 + threadIdx.x;
    if (idx >= total) return;
    int xp = idx % Wp, t = idx / Wp;
    int yp = t % Hp; t /= Hp;
    int cw = t % (C / 32); int b = t / (C / 32);
    int x = xp - pad, y = yp - pad;
    uint32_t word;
    if ((unsigned)x >= (unsigned)W || (unsigned)y >= (unsigned)H) {
        word = 0xFFFFFFFFu;  // pad value -1 -> negative -> bit 1
    } else {
        word = 0u;
        const float* base = in + ((size_t)(b * C + cw * 32) * H + y) * W + x;
        const size_t hw = (size_t)H * W;
        #pragma unroll
        for (int j = 0; j < 32; ++j)
            word |= (base[hw * j] < 0.f) ? (1u << j) : 0u;
    }
    out[idx] = word;
}

// pack conv weights [O,C,KH,KW] -> [O, C/32, KH*KW] u32 (bit j = channel cw*32+j)
__global__ __launch_bounds__(256) void packw_kernel(
    const float* __restrict__ w, uint32_t* __restrict__ out,
    int C, int KK, int total)
{
    int idx = blockIdx.x * 256 + threadIdx.x;
    if (idx >= total) return;
    int kk = idx % KK, t = idx / KK;
    int cw = t % (C / 32); int o = t / (C / 32);
    const float* base = w + ((size_t)o * C + cw * 32) * KK + kk;
    uint32_t word = 0;
    #pragma unroll
    for (int j = 0; j < 32; ++j)
        word |= (base[(size_t)j * KK] < 0.f) ? (1u << j) : 0u;
    out[idx] = word;
}

// pack a row-major [rows, N] fp32 tensor along N into [rows, N/32] u32
__global__ __launch_bounds__(256) void packflat_kernel(
    const float* __restrict__ in, uint32_t* __restrict__ out, int total)
{
    int idx = blockIdx.x * 256 + threadIdx.x;
    if (idx >= total) return;
    const float* base = in + (size_t)idx * 32;
    uint32_t word = 0;
    #pragma unroll
    for (int j = 0; j < 32; ++j)
        word |= (base[j] < 0.f) ? (1u << j) : 0u;
    out[idx] = word;
}

// ---------------------------------------------------------------------------
// binary conv via XOR+popcount. act [B,CW,Hp,Wp] u32, wt [O,CW,KH*KW] u32.
// dot = Kbits - 2*popsum. Optional fused bn (bnp != nullptr).
// ---------------------------------------------------------------------------
template <int CW, int KH, int KW>
__global__ __launch_bounds__(256) void binconv_kernel(
    const uint32_t* __restrict__ pa, const uint32_t* __restrict__ pw,
    float* __restrict__ out, const float* __restrict__ bnp,
    int Hp, int Wp, int Ho, int Wo, int O, int Kbits)
{
    const int b = blockIdx.z, o = blockIdx.y;
    constexpr int NW = CW * KH * KW;
    __shared__ uint32_t wl[NW];
    for (int i = threadIdx.x; i < NW; i += 256) wl[i] = pw[(size_t)o * NW + i];
    __syncthreads();
    int pos = blockIdx.x * 256 + threadIdx.x;
    if (pos >= Ho * Wo) return;
    int y = pos / Wo, x = pos % Wo;
    const uint32_t* pab = pa + (size_t)b * CW * Hp * Wp;
    int sum = 0;
    #pragma unroll
    for (int cw = 0; cw < CW; ++cw) {
        #pragma unroll
        for (int kh = 0; kh < KH; ++kh) {
            const uint32_t* row = pab + ((size_t)(cw * Hp) + y + kh) * Wp + x;
            const uint32_t* wr = wl + (cw * KH + kh) * KW;
            #pragma unroll
            for (int kw = 0; kw < KW; ++kw)
                sum += __popc(row[kw] ^ wr[kw]);
        }
    }
    float dot = (float)(Kbits - 2 * sum);
    if (bnp) dot = bn_apply(bnp, O, o, dot);
    out[((size_t)(b * O + o) * Ho + y) * Wo + x] = dot;
}

// ---------------------------------------------------------------------------
// binary FC: out[b,o] = Kbits - 2*popcount(x[b,:] ^ w[o,:]), + bn (+relu)
// ---------------------------------------------------------------------------
template <int KWRD>
__global__ __launch_bounds__(256) void bingemm_kernel(
    const uint32_t* __restrict__ xp, const uint32_t* __restrict__ wp,
    float* __restrict__ out, const float* __restrict__ bnp,
    int Kbits, int O, int relu)
{
    const int b = blockIdx.y;
    __shared__ uint32_t xl[KWRD];
    for (int i = threadIdx.x; i < KWRD; i += 256) xl[i] = xp[(size_t)b * KWRD + i];
    __syncthreads();
    int o = blockIdx.x * 256 + threadIdx.x;
    if (o >= O) return;
    const uint32_t* wr = wp + (size_t)o * KWRD;
    int sum = 0;
    #pragma unroll 4
    for (int k = 0; k < KWRD; ++k) sum += __popc(xl[k] ^ wr[k]);
    float dot = (float)(Kbits - 2 * sum);
    if (bnp) dot = bn_apply(bnp, O, o, dot);
    if (relu) dot = fmaxf(dot, 0.f);
    out[(size_t)b * O + o] = dot;
}

// ---------------------------------------------------------------------------
// fc3: [128,4096] x [1000,4096]^T + bias. Register-tiled fp32 with K-split
// for parallelism. part layout: [ksplit=8][128][1024]
// ---------------------------------------------------------------------------
__global__ __launch_bounds__(256) void fc3_partial_kernel(
    const float* __restrict__ in, const float* __restrict__ w, float* __restrict__ part)
{
    const int otile = blockIdx.x * 64;
    const int kbase = blockIdx.y * 512;
    __shared__ float xs[32][132];
    __shared__ float wt[32][68];
    const int tid = threadIdx.x;
    const int ox = (tid & 15) * 4;   // 4 consecutive o per thread
    const int bx = (tid >> 4) * 8;   // 8 consecutive b per thread
    float acc[4][8];
    #pragma unroll
    for (int i = 0; i < 4; ++i)
        #pragma unroll
        for (int j = 0; j < 8; ++j) acc[i][j] = 0.f;

    for (int kc = 0; kc < 512; kc += 32) {
        __syncthreads();
        #pragma unroll
        for (int j = 0; j < 16; ++j) {          // 4096 x-tile elems
            int idx = tid + j * 256;
            int bb = idx >> 5, kk = idx & 31;
            xs[kk][bb] = in[(size_t)bb * 4096 + kbase + kc + kk];
        }
        #pragma unroll
        for (int j = 0; j < 8; ++j) {           // 2048 w-tile elems
            int idx = tid + j * 256;
            int oo = idx >> 5, kk = idx & 31;
            int og = otile + oo;
            wt[kk][oo] = (og < 1000) ? w[(size_t)og * 4096 + kbase + kc + kk] : 0.f;
        }
        __syncthreads();
        #pragma unroll
        for (int kk = 0; kk < 32; ++kk) {
            float4 wv = *(const float4*)&wt[kk][ox];
            float4 x0 = *(const float4*)&xs[kk][bx];
            float4 x1 = *(const float4*)&xs[kk][bx + 4];
            float wvv[4] = {wv.x, wv.y, wv.z, wv.w};
            float xv[8]  = {x0.x, x0.y, x0.z, x0.w, x1.x, x1.y, x1.z, x1.w};
            #pragma unroll
            for (int i = 0; i < 4; ++i)
                #pragma unroll
                for (int j = 0; j < 8; ++j)
                    acc[i][j] = fmaf(wvv[i], xv[j], acc[i][j]);
        }
    }
    float* pb = part + (size_t)blockIdx.y * 128 * 1024;
    #pragma unroll
    for (int i = 0; i < 4; ++i)
        #pragma unroll
        for (int j = 0; j < 8; ++j)
            pb[(size_t)(bx + j) * 1024 + otile + ox + i] = acc[i][j];
}

__global__ __launch_bounds__(256) void fc3_reduce_kernel(
    const float* __restrict__ part, const float* __restrict__ bias,
    float* __restrict__ out)
{
    int idx = blockIdx.x * 256 + threadIdx.x;  // b*1000 + o
    if (idx >= 128 * 1000) return;
    int o = idx % 1000, b = idx / 1000;
    float s = bias[o];
    #pragma unroll
    for (int k = 0; k < 8; ++k)
        s += part[((size_t)k * 128 + b) * 1024 + o];
    out[idx] = s;
}

// ---------------------------------------------------------------------------
// launch
// ---------------------------------------------------------------------------
extern "C" void kernel_launch(void* const* d_in, const int* in_sizes, int n_in,
                              void* d_out, int out_size, void* d_ws, size_t ws_size,
                              hipStream_t stream)
{
    const float* x        = (const float*)d_in[0];
    const float* conv1_w  = (const float*)d_in[1];
    const float* bconv2_w = (const float*)d_in[2];
    const float* bconv3_w = (const float*)d_in[3];
    const float* bconv4_w = (const float*)d_in[4];
    const float* bconv5_w = (const float*)d_in[5];
    const float* blin1_w  = (const float*)d_in[6];
    const float* blin2_w  = (const float*)d_in[7];
    const float* lin3_w   = (const float*)d_in[8];
    const float* lin3_b   = (const float*)d_in[9];
    const float* bn1 = (const float*)d_in[10];
    const float* bn2 = (const float*)d_in[11];
    const float* bn3 = (const float*)d_in[12];
    const float* bn4 = (const float*)d_in[13];
    const float* bn5 = (const float*)d_in[14];
    const float* bn6 = (const float*)d_in[15];
    const float* bn7 = (const float*)d_in[16];
    float* out = (float*)d_out;

    // workspace layout (bytes, all 256-aligned)
    char* ws = (char*)d_ws;
    float*    A    = (float*)(ws + 0);               // 148,684,800 B (conv1 out max)
    float*    Bb   = (float*)(ws + 148684800);       //  35,831,808 B
    uint32_t* PA   = (uint32_t*)(ws + 184516608);    //   1,476,096 B (packed acts)
    uint32_t* PW   = (uint32_t*)(ws + 185992704);    //     165,888 B (packed conv w)
    uint32_t* PWF1 = (uint32_t*)(ws + 186158592);    //   4,718,592 B
    uint32_t* PWF2 = (uint32_t*)(ws + 190877184);    //   2,097,152 B
    float*    PART = (float*)(ws + 192974336);       //   4,194,304 B
    // wt2 (conv1 transposed weights, 557,568 B) aliases PART: PART is only
    // live at steps 23-24; wt2 only at step 1. No temporal overlap.
    float*    WT2  = PART;

    // 0) transpose conv1 weights -> WT2 [3][11][96][11]
    conv1_transpose_w<<<(96 * 363 + 255) / 256, 256, 0, stream>>>(conv1_w, WT2);

    // 1) conv1 -> A [128,96,55,55]
    conv1_kernel<<<dim3(55, 3, 128), 256, 0, stream>>>(x, WT2, A);

    // 2) maxpool + bn1 -> Bb [128,96,27,27]
    {
        int total = 128 * 96 * 27 * 27;
        pool_bn_kernel<<<(total + 255) / 256, 256, 0, stream>>>(A, Bb, bn1, 96, 55, 55, 27, 27, total);
    }
    // 3) binarize+pad2+pack -> PA [128,3,31,31]
    {
        int total = 128 * 3 * 31 * 31;
        binpack_pad_kernel<<<(total + 255) / 256, 256, 0, stream>>>(Bb, PA, 96, 27, 27, 2, 31, 31, total);
    }
    // 4) pack bconv2_w -> PW [256,3,25]
    {
        int total = 256 * 3 * 25;
        packw_kernel<<<(total + 255) / 256, 256, 0, stream>>>(bconv2_w, PW, 96, 25, total);
    }
    // 5) binconv2 -> A [128,256,27,27]
    binconv_kernel<3, 5, 5><<<dim3(3, 256, 128), 256, 0, stream>>>(
        PA, PW, A, nullptr, 31, 31, 27, 27, 256, 2400);

    // 6) maxpool + bn2 -> Bb [128,256,13,13]
    {
        int total = 128 * 256 * 13 * 13;
        pool_bn_kernel<<<(total + 255) / 256, 256, 0, stream>>>(A, Bb, bn2, 256, 27, 27, 13, 13, total);
    }
    // 7) binarize+pad1+pack -> PA [128,8,15,15]
    {
        int total = 128 * 8 * 15 * 15;
        binpack_pad_kernel<<<(total + 255) / 256, 256, 0, stream>>>(Bb, PA, 256, 13, 13, 1, 15, 15, total);
    }
    // 8) pack bconv3_w
    {
        int total = 384 * 8 * 9;
        packw_kernel<<<(total + 255) / 256, 256, 0, stream>>>(bconv3_w, PW, 256, 9, total);
    }
    // 9) binconv3 + bn3 -> A [128,384,13,13]
    binconv_kernel<8, 3, 3><<<dim3(1, 384, 128), 256, 0, stream>>>(
        PA, PW, A, bn3, 15, 15, 13, 13, 384, 2304);

    // 10) binarize+pad1+pack -> PA [128,12,15,15]
    {
        int total = 128 * 12 * 15 * 15;
        binpack_pad_kernel<<<(total + 255) / 256, 256, 0, stream>>>(A, PA, 384, 13, 13, 1, 15, 15, total);
    }
    // 11) pack bconv4_w
    {
        int total = 384 * 12 * 9;
        packw_kernel<<<(total + 255) / 256, 256, 0, stream>>>(bconv4_w, PW, 384, 9, total);
    }
    // 12) binconv4 + bn4 -> Bb [128,384,13,13]
    binconv_kernel<12, 3, 3><<<dim3(1, 384, 128), 256, 0, stream>>>(
        PA, PW, Bb, bn4, 15, 15, 13, 13, 384, 3456);

    // 13) binarize+pad1+pack -> PA [128,12,15,15]
    {
        int total = 128 * 12 * 15 * 15;
        binpack_pad_kernel<<<(total + 255) / 256, 256, 0, stream>>>(Bb, PA, 384, 13, 13, 1, 15, 15, total);
    }
    // 14) pack bconv5_w
    {
        int total = 256 * 12 * 9;
        packw_kernel<<<(total + 255) / 256, 256, 0, stream>>>(bconv5_w, PW, 384, 9, total);
    }
    // 15) binconv5 (no bn) -> A [128,256,13,13]
    binconv_kernel<12, 3, 3><<<dim3(1, 256, 128), 256, 0, stream>>>(
        PA, PW, A, nullptr, 15, 15, 13, 13, 256, 3456);

    // 16) maxpool + bn5 -> Bb [128,256,6,6]  (flatten = [128,9216])
    {
        int total = 128 * 256 * 6 * 6;
        pool_bn_kernel<<<(total + 255) / 256, 256, 0, stream>>>(A, Bb, bn5, 256, 13, 13, 6, 6, total);
    }
    // 17) pack activations -> PA [128,288]
    {
        int total = 128 * 288;
        packflat_kernel<<<(total + 255) / 256, 256, 0, stream>>>(Bb, PA, total);
    }
    // 18) pack blin1_w -> PWF1 [4096,288]
    {
        int total = 4096 * 288;
        packflat_kernel<<<(total + 255) / 256, 256, 0, stream>>>(blin1_w, PWF1, total);
    }
    // 19) bingemm1 + bn6 -> A [128,4096]
    bingemm_kernel<288><<<dim3(16, 128), 256, 0, stream>>>(PA, PWF1, A, bn6, 9216, 4096, 0);

    // 20) pack activations -> PA [128,128]
    {
        int total = 128 * 128;
        packflat_kernel<<<(total + 255) / 256, 256, 0, stream>>>(A, PA, total);
    }
    // 21) pack blin2_w -> PWF2 [4096,128]
    {
        int total = 4096 * 128;
        packflat_kernel<<<(total + 255) / 256, 256, 0, stream>>>(blin2_w, PWF2, total);
    }
    // 22) bingemm2 + bn7 + relu -> Bb [128,4096]
    bingemm_kernel<128><<<dim3(16, 128), 256, 0, stream>>>(PA, PWF2, Bb, bn7, 4096, 4096, 1);

    // 23) fc3 partial (K-split 8) -> PART [8][128][1024]
    fc3_partial_kernel<<<dim3(16, 8), 256, 0, stream>>>(Bb, lin3_w, PART);

    // 24) reduce + bias -> d_out [128,1000]
    fc3_reduce_kernel<<<(128 * 1000 + 255) / 256, 256, 0, stream>>>(PART, lin3_b, out);
}

// Round 3
// 1186.576 us; speedup vs baseline: 9.9681x; 1.6268x over previous
//
#include <hip/hip_runtime.h>
#include <stdint.h>
#include <math.h>

#define EPS 1e-5f

typedef __attribute__((ext_vector_type(4))) __bf16 bf16x4;
typedef __attribute__((ext_vector_type(8))) __bf16 bf16x8;
typedef __attribute__((ext_vector_type(16))) float f32x16;

// ---------------------------------------------------------------------------
// helpers
// ---------------------------------------------------------------------------
__device__ __forceinline__ float bn_apply(const float* __restrict__ bnp, int C, int c, float x) {
    float g = bnp[c], b = bnp[C + c], m = bnp[2 * C + c], v = bnp[3 * C + c];
    float scale = g / sqrtf(v + EPS);
    return (x - m) * scale + b;
}

// ---------------------------------------------------------------------------
// conv1 weight prep: w [96,3,11,11] fp32 -> hi/lo bf16 in layout
// [otile(3)][krow(33)][o(32)][kw(16)]  (kw 11..15 zero-padded)
// krow = c*11+kh, so src offset = og*363 + kr*11 + kw.
// ---------------------------------------------------------------------------
__global__ __launch_bounds__(256) void conv1_wprep(
    const float* __restrict__ w, __bf16* __restrict__ wth, __bf16* __restrict__ wtl)
{
    int idx = blockIdx.x * 256 + threadIdx.x;
    if (idx >= 96 * 33 * 16) return;
    int kw = idx & 15;
    int kr = (idx >> 4) % 33;
    int og = idx / (16 * 33);
    int ot = og >> 5, o = og & 31;
    float v = 0.f;
    if (kw < 11) v = w[og * 363 + kr * 11 + kw];
    __bf16 h = (__bf16)v;
    size_t dst = ((size_t)(ot * 33 + kr) * 32 + o) * 16 + kw;
    wth[dst] = h;
    wtl[dst] = (__bf16)(v - (float)h);
}

// ---------------------------------------------------------------------------
// conv1 via MFMA (bf16 hi/lo 3-pass, exact to ~2^-17 rel):
// grid (55 oy, 128 b), block 384 = 6 waves; wave = (ot = w>>1, xt = w&1).
// Each wave: 32 o x 32 ox tile, K = 33 krows x 16 kw.
// Input rows staged in LDS as bf16 hi/lo, row stride 264 (528 B).
// ---------------------------------------------------------------------------
__global__ __launch_bounds__(384) void conv1_mfma(
    const float* __restrict__ x, const __bf16* __restrict__ wth,
    const __bf16* __restrict__ wtl, float* __restrict__ out)
{
    const int oy = blockIdx.x;      // 0..54
    const int b  = blockIdx.y;      // 0..127
    __shared__ __bf16 ldsbuf[2 * 33 * 264 + 8];
    __bf16* ldsH = ldsbuf;
    __bf16* ldsL = ldsbuf + 33 * 264;

    // stage 33 padded rows (pos 0..263 <-> ix = pos-2; OOB -> 0), hi/lo bf16
    const float* xb = x + (size_t)b * 3 * 224 * 224;
    for (int idx = threadIdx.x; idx < 33 * 33; idx += 384) {
        int r = idx / 33, q = idx % 33;   // krow, 8-elem chunk
        int c = r / 11, kh = r % 11;
        int iy = 4 * oy + kh - 2;
        const float* src = xb + ((size_t)c * 224 + iy) * 224;
        bf16x8 hv, lv;
        #pragma unroll
        for (int j = 0; j < 8; ++j) {
            int ix = q * 8 + j - 2;
            float v = 0.f;
            if ((unsigned)iy < 224u && (unsigned)ix < 224u) v = src[ix];
            __bf16 h = (__bf16)v;
            hv[j] = h;
            lv[j] = (__bf16)(v - (float)h);
        }
        *(bf16x8*)(ldsH + r * 264 + q * 8) = hv;
        *(bf16x8*)(ldsL + r * 264 + q * 8) = lv;
    }
    __syncthreads();

    const int wv = threadIdx.x >> 6;
    const int l  = threadIdx.x & 63;
    const int ot = wv >> 1, xt = wv & 1;
    const int col = l & 31, kg = l >> 5;

    f32x16 acc = {};
    const int bpos = 4 * (xt * 32 + col) + 8 * kg;   // element offset in row
    const int wofs = col * 16 + kg * 8;              // element offset in weight krow-chunk

    for (int kr = 0; kr < 33; ++kr) {
        const size_t wko = (size_t)(ot * 33 + kr) * 512 + wofs;
        bf16x8 ah = *(const bf16x8*)(wth + wko);
        bf16x8 al = *(const bf16x8*)(wtl + wko);
        const __bf16* rH = ldsH + kr * 264 + bpos;
        const __bf16* rL = ldsL + kr * 264 + bpos;
        bf16x4 bh0 = *(const bf16x4*)rH;
        bf16x4 bh1 = *(const bf16x4*)(rH + 4);
        bf16x4 bl0 = *(const bf16x4*)rL;
        bf16x4 bl1 = *(const bf16x4*)(rL + 4);
        bf16x8 bh = __builtin_shufflevector(bh0, bh1, 0, 1, 2, 3, 4, 5, 6, 7);
        bf16x8 bl = __builtin_shufflevector(bl0, bl1, 0, 1, 2, 3, 4, 5, 6, 7);
        acc = __builtin_amdgcn_mfma_f32_32x32x16_bf16(ah, bh, acc, 0, 0, 0);
        acc = __builtin_amdgcn_mfma_f32_32x32x16_bf16(ah, bl, acc, 0, 0, 0);
        acc = __builtin_amdgcn_mfma_f32_32x32x16_bf16(al, bh, acc, 0, 0, 0);
    }

    const int ox = xt * 32 + col;
    if (ox < 55) {
        float* ob = out + ((size_t)(b * 96 + ot * 32) * 55 + oy) * 55 + ox;
        #pragma unroll
        for (int i = 0; i < 16; ++i) {
            int row = (i & 3) + 8 * (i >> 2) + 4 * kg;
            ob[(size_t)row * 55 * 55] = acc[i];
        }
    }
}

// ---------------------------------------------------------------------------
// fused maxpool(3x3, stride2, VALID) + BN (pool BEFORE bn, per reference)
// ---------------------------------------------------------------------------
__global__ __launch_bounds__(256) void pool_bn_kernel(
    const float* __restrict__ in, float* __restrict__ out,
    const float* __restrict__ bnp,
    int C, int Hi, int Wi, int Ho, int Wo, int total)
{
    int idx = blockIdx.x * 256 + threadIdx.x;
    if (idx >= total) return;
    int x = idx % Wo, t = idx / Wo;
    int y = t % Ho; t /= Ho;
    int c = t % C;  int b = t / C;
    const float* base = in + ((size_t)(b * C + c) * Hi + 2 * y) * Wi + 2 * x;
    float m = -INFINITY;
    #pragma unroll
    for (int j = 0; j < 3; ++j)
        #pragma unroll
        for (int i = 0; i < 3; ++i)
            m = fmaxf(m, base[(size_t)j * Wi + i]);
    out[idx] = bn_apply(bnp, C, c, m);
}

// ---------------------------------------------------------------------------
// binarize + pad(-1) + bitpack along C: in [B,C,H,W] fp32 ->
// out [B, C/32, H+2p, W+2p] u32, bit j = (value < 0), pad word = all ones
// ---------------------------------------------------------------------------
__global__ __launch_bounds__(256) void binpack_pad_kernel(
    const float* __restrict__ in, uint32_t* __restrict__ out,
    int C, int H, int W, int pad, int Hp, int Wp, int total)
{
    int idx = blockIdx.x * 256 + threadIdx.x;
    if (idx >= total) return;
    int xp = idx % Wp, t = idx / Wp;
    int yp = t % Hp; t /= Hp;
    int cw = t % (C / 32); int b = t / (C / 32);
    int x = xp - pad, y = yp - pad;
    uint32_t word;
    if ((unsigned)x >= (unsigned)W || (unsigned)y >= (unsigned)H) {
        word = 0xFFFFFFFFu;  // pad value -1 -> negative -> bit 1
    } else {
        word = 0u;
        const float* base = in + ((size_t)(b * C + cw * 32) * H + y) * W + x;
        const size_t hw = (size_t)H * W;
        #pragma unroll
        for (int j = 0; j < 32; ++j)
            word |= (base[hw * j] < 0.f) ? (1u << j) : 0u;
    }
    out[idx] = word;
}

// pack conv weights [O,C,KH,KW] -> [O, C/32, KH*KW] u32 (bit j = channel cw*32+j)
__global__ __launch_bounds__(256) void packw_kernel(
    const float* __restrict__ w, uint32_t* __restrict__ out,
    int C, int KK, int total)
{
    int idx = blockIdx.x * 256 + threadIdx.x;
    if (idx >= total) return;
    int kk = idx % KK, t = idx / KK;
    int cw = t % (C / 32); int o = t / (C / 32);
    const float* base = w + ((size_t)o * C + cw * 32) * KK + kk;
    uint32_t word = 0;
    #pragma unroll
    for (int j = 0; j < 32; ++j)
        word |= (base[(size_t)j * KK] < 0.f) ? (1u << j) : 0u;
    out[idx] = word;
}

// pack a row-major [rows, N] fp32 tensor along N into [rows, N/32] u32
__global__ __launch_bounds__(256) void packflat_kernel(
    const float* __restrict__ in, uint32_t* __restrict__ out, int total)
{
    int idx = blockIdx.x * 256 + threadIdx.x;
    if (idx >= total) return;
    const float* base = in + (size_t)idx * 32;
    uint32_t word = 0;
    #pragma unroll
    for (int j = 0; j < 32; ++j)
        word |= (base[j] < 0.f) ? (1u << j) : 0u;
    out[idx] = word;
}

// ---------------------------------------------------------------------------
// binary conv via XOR+popcount. act [B,CW,Hp,Wp] u32, wt [O,CW,KH*KW] u32.
// dot = Kbits - 2*popsum. Optional fused bn (bnp != nullptr).
// ---------------------------------------------------------------------------
template <int CW, int KH, int KW>
__global__ __launch_bounds__(256) void binconv_kernel(
    const uint32_t* __restrict__ pa, const uint32_t* __restrict__ pw,
    float* __restrict__ out, const float* __restrict__ bnp,
    int Hp, int Wp, int Ho, int Wo, int O, int Kbits)
{
    const int b = blockIdx.z, o = blockIdx.y;
    constexpr int NW = CW * KH * KW;
    __shared__ uint32_t wl[NW];
    for (int i = threadIdx.x; i < NW; i += 256) wl[i] = pw[(size_t)o * NW + i];
    __syncthreads();
    int pos = blockIdx.x * 256 + threadIdx.x;
    if (pos >= Ho * Wo) return;
    int y = pos / Wo, x = pos % Wo;
    const uint32_t* pab = pa + (size_t)b * CW * Hp * Wp;
    int sum = 0;
    #pragma unroll
    for (int cw = 0; cw < CW; ++cw) {
        #pragma unroll
        for (int kh = 0; kh < KH; ++kh) {
            const uint32_t* row = pab + ((size_t)(cw * Hp) + y + kh) * Wp + x;
            const uint32_t* wr = wl + (cw * KH + kh) * KW;
            #pragma unroll
            for (int kw = 0; kw < KW; ++kw)
                sum += __popc(row[kw] ^ wr[kw]);
        }
    }
    float dot = (float)(Kbits - 2 * sum);
    if (bnp) dot = bn_apply(bnp, O, o, dot);
    out[((size_t)(b * O + o) * Ho + y) * Wo + x] = dot;
}

// ---------------------------------------------------------------------------
// binary FC: out[b,o] = Kbits - 2*popcount(x[b,:] ^ w[o,:]), + bn (+relu)
// ---------------------------------------------------------------------------
template <int KWRD>
__global__ __launch_bounds__(256) void bingemm_kernel(
    const uint32_t* __restrict__ xp, const uint32_t* __restrict__ wp,
    float* __restrict__ out, const float* __restrict__ bnp,
    int Kbits, int O, int relu)
{
    const int b = blockIdx.y;
    __shared__ uint32_t xl[KWRD];
    for (int i = threadIdx.x; i < KWRD; i += 256) xl[i] = xp[(size_t)b * KWRD + i];
    __syncthreads();
    int o = blockIdx.x * 256 + threadIdx.x;
    if (o >= O) return;
    const uint32_t* wr = wp + (size_t)o * KWRD;
    int sum = 0;
    #pragma unroll 4
    for (int k = 0; k < KWRD; ++k) sum += __popc(xl[k] ^ wr[k]);
    float dot = (float)(Kbits - 2 * sum);
    if (bnp) dot = bn_apply(bnp, O, o, dot);
    if (relu) dot = fmaxf(dot, 0.f);
    out[(size_t)b * O + o] = dot;
}

// ---------------------------------------------------------------------------
// fc3: [128,4096] x [1000,4096]^T + bias. Register-tiled fp32 with K-split
// for parallelism. part layout: [ksplit=8][128][1024]
// ---------------------------------------------------------------------------
__global__ __launch_bounds__(256) void fc3_partial_kernel(
    const float* __restrict__ in, const float* __restrict__ w, float* __restrict__ part)
{
    const int otile = blockIdx.x * 64;
    const int kbase = blockIdx.y * 512;
    __shared__ float xs[32][132];
    __shared__ float wt[32][68];
    const int tid = threadIdx.x;
    const int ox = (tid & 15) * 4;   // 4 consecutive o per thread
    const int bx = (tid >> 4) * 8;   // 8 consecutive b per thread
    float acc[4][8];
    #pragma unroll
    for (int i = 0; i < 4; ++i)
        #pragma unroll
        for (int j = 0; j < 8; ++j) acc[i][j] = 0.f;

    for (int kc = 0; kc < 512; kc += 32) {
        __syncthreads();
        #pragma unroll
        for (int j = 0; j < 16; ++j) {          // 4096 x-tile elems
            int idx = tid + j * 256;
            int bb = idx >> 5, kk = idx & 31;
            xs[kk][bb] = in[(size_t)bb * 4096 + kbase + kc + kk];
        }
        #pragma unroll
        for (int j = 0; j < 8; ++j) {           // 2048 w-tile elems
            int idx = tid + j * 256;
            int oo = idx >> 5, kk = idx & 31;
            int og = otile + oo;
            wt[kk][oo] = (og < 1000) ? w[(size_t)og * 4096 + kbase + kc + kk] : 0.f;
        }
        __syncthreads();
        #pragma unroll
        for (int kk = 0; kk < 32; ++kk) {
            float4 wv = *(const float4*)&wt[kk][ox];
            float4 x0 = *(const float4*)&xs[kk][bx];
            float4 x1 = *(const float4*)&xs[kk][bx + 4];
            float wvv[4] = {wv.x, wv.y, wv.z, wv.w};
            float xv[8]  = {x0.x, x0.y, x0.z, x0.w, x1.x, x1.y, x1.z, x1.w};
            #pragma unroll
            for (int i = 0; i < 4; ++i)
                #pragma unroll
                for (int j = 0; j < 8; ++j)
                    acc[i][j] = fmaf(wvv[i], xv[j], acc[i][j]);
        }
    }
    float* pb = part + (size_t)blockIdx.y * 128 * 1024;
    #pragma unroll
    for (int i = 0; i < 4; ++i)
        #pragma unroll
        for (int j = 0; j < 8; ++j)
            pb[(size_t)(bx + j) * 1024 + otile + ox + i] = acc[i][j];
}

__global__ __launch_bounds__(256) void fc3_reduce_kernel(
    const float* __restrict__ part, const float* __restrict__ bias,
    float* __restrict__ out)
{
    int idx = blockIdx.x * 256 + threadIdx.x;  // b*1000 + o
    if (idx >= 128 * 1000) return;
    int o = idx % 1000, b = idx / 1000;
    float s = bias[o];
    #pragma unroll
    for (int k = 0; k < 8; ++k)
        s += part[((size_t)k * 128 + b) * 1024 + o];
    out[idx] = s;
}

// ---------------------------------------------------------------------------
// launch
// ---------------------------------------------------------------------------
extern "C" void kernel_launch(void* const* d_in, const int* in_sizes, int n_in,
                              void* d_out, int out_size, void* d_ws, size_t ws_size,
                              hipStream_t stream)
{
    const float* x        = (const float*)d_in[0];
    const float* conv1_w  = (const float*)d_in[1];
    const float* bconv2_w = (const float*)d_in[2];
    const float* bconv3_w = (const float*)d_in[3];
    const float* bconv4_w = (const float*)d_in[4];
    const float* bconv5_w = (const float*)d_in[5];
    const float* blin1_w  = (const float*)d_in[6];
    const float* blin2_w  = (const float*)d_in[7];
    const float* lin3_w   = (const float*)d_in[8];
    const float* lin3_b   = (const float*)d_in[9];
    const float* bn1 = (const float*)d_in[10];
    const float* bn2 = (const float*)d_in[11];
    const float* bn3 = (const float*)d_in[12];
    const float* bn4 = (const float*)d_in[13];
    const float* bn5 = (const float*)d_in[14];
    const float* bn6 = (const float*)d_in[15];
    const float* bn7 = (const float*)d_in[16];
    float* out = (float*)d_out;

    // workspace layout (bytes, all 256-aligned)
    char* ws = (char*)d_ws;
    float*    A    = (float*)(ws + 0);               // 148,684,800 B (conv1 out max)
    float*    Bb   = (float*)(ws + 148684800);       //  35,831,808 B
    uint32_t* PA   = (uint32_t*)(ws + 184516608);    //   1,476,096 B (packed acts)
    uint32_t* PW   = (uint32_t*)(ws + 185992704);    //     165,888 B (packed conv w)
    uint32_t* PWF1 = (uint32_t*)(ws + 186158592);    //   4,718,592 B
    uint32_t* PWF2 = (uint32_t*)(ws + 190877184);    //   2,097,152 B
    float*    PART = (float*)(ws + 192974336);       //   4,194,304 B
    // conv1 bf16 hi/lo weights (101,376 B each) alias PART: PART live only
    // at steps 23-24, weights only at step 1. No temporal overlap.
    __bf16*   WTH  = (__bf16*)(ws + 192974336);
    __bf16*   WTL  = (__bf16*)(ws + 192974336 + 102400);

    // 0) prep conv1 weights (hi/lo bf16, k-padded layout)
    conv1_wprep<<<(96 * 33 * 16 + 255) / 256, 256, 0, stream>>>(conv1_w, WTH, WTL);

    // 1) conv1 via MFMA -> A [128,96,55,55]
    conv1_mfma<<<dim3(55, 128), 384, 0, stream>>>(x, WTH, WTL, A);

    // 2) maxpool + bn1 -> Bb [128,96,27,27]
    {
        int total = 128 * 96 * 27 * 27;
        pool_bn_kernel<<<(total + 255) / 256, 256, 0, stream>>>(A, Bb, bn1, 96, 55, 55, 27, 27, total);
    }
    // 3) binarize+pad2+pack -> PA [128,3,31,31]
    {
        int total = 128 * 3 * 31 * 31;
        binpack_pad_kernel<<<(total + 255) / 256, 256, 0, stream>>>(Bb, PA, 96, 27, 27, 2, 31, 31, total);
    }
    // 4) pack bconv2_w -> PW [256,3,25]
    {
        int total = 256 * 3 * 25;
        packw_kernel<<<(total + 255) / 256, 256, 0, stream>>>(bconv2_w, PW, 96, 25, total);
    }
    // 5) binconv2 -> A [128,256,27,27]
    binconv_kernel<3, 5, 5><<<dim3(3, 256, 128), 256, 0, stream>>>(
        PA, PW, A, nullptr, 31, 31, 27, 27, 256, 2400);

    // 6) maxpool + bn2 -> Bb [128,256,13,13]
    {
        int total = 128 * 256 * 13 * 13;
        pool_bn_kernel<<<(total + 255) / 256, 256, 0, stream>>>(A, Bb, bn2, 256, 27, 27, 13, 13, total);
    }
    // 7) binarize+pad1+pack -> PA [128,8,15,15]
    {
        int total = 128 * 8 * 15 * 15;
        binpack_pad_kernel<<<(total + 255) / 256, 256, 0, stream>>>(Bb, PA, 256, 13, 13, 1, 15, 15, total);
    }
    // 8) pack bconv3_w
    {
        int total = 384 * 8 * 9;
        packw_kernel<<<(total + 255) / 256, 256, 0, stream>>>(bconv3_w, PW, 256, 9, total);
    }
    // 9) binconv3 + bn3 -> A [128,384,13,13]
    binconv_kernel<8, 3, 3><<<dim3(1, 384, 128), 256, 0, stream>>>(
        PA, PW, A, bn3, 15, 15, 13, 13, 384, 2304);

    // 10) binarize+pad1+pack -> PA [128,12,15,15]
    {
        int total = 128 * 12 * 15 * 15;
        binpack_pad_kernel<<<(total + 255) / 256, 256, 0, stream>>>(A, PA, 384, 13, 13, 1, 15, 15, total);
    }
    // 11) pack bconv4_w
    {
        int total = 384 * 12 * 9;
        packw_kernel<<<(total + 255) / 256, 256, 0, stream>>>(bconv4_w, PW, 384, 9, total);
    }
    // 12) binconv4 + bn4 -> Bb [128,384,13,13]
    binconv_kernel<12, 3, 3><<<dim3(1, 384, 128), 256, 0, stream>>>(
        PA, PW, Bb, bn4, 15, 15, 13, 13, 384, 3456);

    // 13) binarize+pad1+pack -> PA [128,12,15,15]
    {
        int total = 128 * 12 * 15 * 15;
        binpack_pad_kernel<<<(total + 255) / 256, 256, 0, stream>>>(Bb, PA, 384, 13, 13, 1, 15, 15, total);
    }
    // 14) pack bconv5_w
    {
        int total = 256 * 12 * 9;
        packw_kernel<<<(total + 255) / 256, 256, 0, stream>>>(bconv5_w, PW, 384, 9, total);
    }
    // 15) binconv5 (no bn) -> A [128,256,13,13]
    binconv_kernel<12, 3, 3><<<dim3(1, 256, 128), 256, 0, stream>>>(
        PA, PW, A, nullptr, 15, 15, 13, 13, 256, 3456);

    // 16) maxpool + bn5 -> Bb [128,256,6,6]  (flatten = [128,9216])
    {
        int total = 128 * 256 * 6 * 6;
        pool_bn_kernel<<<(total + 255) / 256, 256, 0, stream>>>(A, Bb, bn5, 256, 13, 13, 6, 6, total);
    }
    // 17) pack activations -> PA [128,288]
    {
        int total = 128 * 288;
        packflat_kernel<<<(total + 255) / 256, 256, 0, stream>>>(Bb, PA, total);
    }
    // 18) pack blin1_w -> PWF1 [4096,288]
    {
        int total = 4096 * 288;
        packflat_kernel<<<(total + 255) / 256, 256, 0, stream>>>(blin1_w, PWF1, total);
    }
    // 19) bingemm1 + bn6 -> A [128,4096]
    bingemm_kernel<288><<<dim3(16, 128), 256, 0, stream>>>(PA, PWF1, A, bn6, 9216, 4096, 0);

    // 20) pack activations -> PA [128,128]
    {
        int total = 128 * 128;
        packflat_kernel<<<(total + 255) / 256, 256, 0, stream>>>(A, PA, total);
    }
    // 21) pack blin2_w -> PWF2 [4096,128]
    {
        int total = 4096 * 128;
        packflat_kernel<<<(total + 255) / 256, 256, 0, stream>>>(blin2_w, PWF2, total);
    }
    // 22) bingemm2 + bn7 + relu -> Bb [128,4096]
    bingemm_kernel<128><<<dim3(16, 128), 256, 0, stream>>>(PA, PWF2, Bb, bn7, 4096, 4096, 1);

    // 23) fc3 partial (K-split 8) -> PART [8][128][1024]
    fc3_partial_kernel<<<dim3(16, 8), 256, 0, stream>>>(Bb, lin3_w, PART);

    // 24) reduce + bias -> d_out [128,1000]
    fc3_reduce_kernel<<<(128 * 1000 + 255) / 256, 256, 0, stream>>>(PART, lin3_b, out);
}